// Round 1
// 523.409 us; speedup vs baseline: 1.1997x; 1.1997x over previous
//
#include <hip/hip_runtime.h>
#include <math.h>
#include <stdint.h>

#define T_DIM 2048
#define B_DIM 16
#define D_DIM 1024
#define N_DIM 64
#define EPSV 1e-6f

#define NT 256   // proj row length: 0-63 k, 64-127 v, 128-191 q, 192-255 sigmoid(beta)

#define TWO_LOG2E 2.885390081777927f   // 2*log2(e)
#define LOG2E     1.4426950408889634f

// ---- fast math ----
__device__ __forceinline__ float fast_rcp(float x) {
    return __builtin_amdgcn_rcpf(x);
}
__device__ __forceinline__ float sigmoid_fast(float x) {
    return fast_rcp(1.f + __builtin_amdgcn_exp2f(-LOG2E * x));
}
__device__ __forceinline__ float tanh_from_scaled(float xs) {
    float e = __builtin_amdgcn_exp2f(xs);
    return 1.f - 2.f * fast_rcp(e + 1.f);
}

// DPP all-reduce within each 16-lane row.
template<int CTRL>
__device__ __forceinline__ float dpp_radd(float x) {
    int y = __builtin_amdgcn_update_dpp(0, __float_as_int(x), CTRL, 0xf, 0xf, true);
    return x + __int_as_float(y);
}
__device__ __forceinline__ float reduce16(float x) {
    x = dpp_radd<0xB1>(x);    // quad_perm [1,0,3,2]
    x = dpp_radd<0x4E>(x);    // quad_perm [2,3,0,1]
    x = dpp_radd<0x124>(x);   // row_ror:4
    x = dpp_radd<0x128>(x);   // row_ror:8
    return x;
}

// async global -> LDS DMA, 16 B per lane; LDS base wave-uniform, lane i -> base + 16*i
__device__ __forceinline__ void dma16(const float* g, float* l) {
    __builtin_amdgcn_global_load_lds((const __attribute__((address_space(1))) void*)g,
                                     (__attribute__((address_space(3))) void*)l, 16, 0, 0);
}

// ======================= MFMA projection GEMM =======================
// proj[m][c] = sum_k x[m][k] * W[c][k], W = rows of {Wk,Wv,Wq,Wb}.
// fp32 emulated as bf16 split: x = xh + xl (trunc split, residual exact);
// acc += xh*wh + xh*wl + xl*wh  (dropped xl*wl ~ 2^-16 relative).
// Tile: BM=128 x BN=256, BK=32 fp32, 4 waves, wave-tile 64x128 of 32x32x16 MFMA.
typedef __bf16 bf16x8_t __attribute__((ext_vector_type(8)));
typedef float  f32x16_t __attribute__((ext_vector_type(16)));

union FragU { uint32_t u[4]; bf16x8_t v; };

#define BM 128
#define BK 32

// LDS tiles: [row][32 floats], 16B k-slots XOR-swizzled: phys_slot = s ^ (row&7).
// Read 8 consecutive fp32 (2 aligned slots; XOR keeps the pair aligned) and
// split into bf16 hi/lo fragments.
__device__ __forceinline__ void load_frag_pair(const float* __restrict__ tile,
                                               int row, int s,
                                               bf16x8_t& hi, bf16x8_t& lo)
{
    const int sw = row & 7;
    const float4 f0 = *(const float4*)(tile + row * BK + 4 * (s ^ sw));
    const float4 f1 = *(const float4*)(tile + row * BK + 4 * ((s + 1) ^ sw));
    float f[8] = {f0.x, f0.y, f0.z, f0.w, f1.x, f1.y, f1.z, f1.w};
    FragU h, l;
    #pragma unroll
    for (int j = 0; j < 4; ++j) {
        uint32_t u0 = __float_as_uint(f[2 * j]);
        uint32_t u1 = __float_as_uint(f[2 * j + 1]);
        h.u[j] = (u1 & 0xffff0000u) | (u0 >> 16);          // packed hi bf16 pair
        float r0 = f[2 * j]     - __uint_as_float(u0 & 0xffff0000u);
        float r1 = f[2 * j + 1] - __uint_as_float(u1 & 0xffff0000u);
        l.u[j] = (__float_as_uint(r1) & 0xffff0000u) | (__float_as_uint(r0) >> 16);
    }
    hi = h.v; lo = l.v;
}

__global__ __launch_bounds__(256) void proj_gemm_mfma(
    const float* __restrict__ x,
    const float* __restrict__ Wk, const float* __restrict__ Wv,
    const float* __restrict__ Wq, const float* __restrict__ Wb,
    const float* __restrict__ bb,
    float* __restrict__ proj)
{
    __shared__ float As[2][BM * BK];   // 2 x 16 KB
    __shared__ float Bs[2][NT * BK];   // 2 x 32 KB

    const int tid  = threadIdx.x;
    const int w    = tid >> 6;         // wave 0..3
    const int lane = tid & 63;
    const int m0   = blockIdx.x * BM;

    const int lrow8 = lane >> 3;              // row-within-8 for DMA
    const int lslot = (lane & 7) ^ lrow8;     // pre-swizzled source slot (G21)

    const int wm = w >> 1, wn = w & 1;        // wave tile 64(M) x 128(N)
    const int cl = lane & 31;                 // row/col within a 32x32 tile
    const int kh = lane >> 5;                 // k-half selector

    f32x16_t acc[2][4] = {};

    auto stage = [&](int buf, int kb) {
        // A: wave w stages rows [32w, 32w+32), 4 DMAs of 8 rows (1 KB each)
        #pragma unroll
        for (int i = 0; i < 4; ++i) {
            const int rb = w * 32 + i * 8;
            const int m  = rb + lrow8;
            dma16(x + (size_t)(m0 + m) * D_DIM + kb + 4 * lslot, &As[buf][rb * BK]);
        }
        // B: wave w stages rows [64w, 64w+64), 8 DMAs of 8 rows
        #pragma unroll
        for (int i = 0; i < 8; ++i) {
            const int rb = w * 64 + i * 8;
            const int n  = rb + lrow8;                 // 0..255, uniform 64-range per DMA
            const float* Wsrc = (n < 64) ? Wk : (n < 128) ? Wv : (n < 192) ? Wq : Wb;
            dma16(Wsrc + (size_t)(n & 63) * D_DIM + kb + 4 * lslot, &Bs[buf][rb * BK]);
        }
    };

    auto compute = [&](int buf) {
        const float* At = As[buf];
        const float* Bt = Bs[buf];
        #pragma unroll
        for (int ksub = 0; ksub < 2; ++ksub) {
            const int s = ksub * 4 + kh * 2;           // logical 16B slot of this lane's k
            bf16x8_t ah[2], al[2], bh[4], bl[4];
            #pragma unroll
            for (int tm = 0; tm < 2; ++tm)
                load_frag_pair(At, wm * 64 + tm * 32 + cl, s, ah[tm], al[tm]);
            #pragma unroll
            for (int tn = 0; tn < 4; ++tn)
                load_frag_pair(Bt, wn * 128 + tn * 32 + cl, s, bh[tn], bl[tn]);
            #pragma unroll
            for (int tm = 0; tm < 2; ++tm)
                #pragma unroll
                for (int tn = 0; tn < 4; ++tn) {
                    acc[tm][tn] = __builtin_amdgcn_mfma_f32_32x32x16_bf16(ah[tm], bh[tn], acc[tm][tn], 0, 0, 0);
                    acc[tm][tn] = __builtin_amdgcn_mfma_f32_32x32x16_bf16(ah[tm], bl[tn], acc[tm][tn], 0, 0, 0);
                    acc[tm][tn] = __builtin_amdgcn_mfma_f32_32x32x16_bf16(al[tm], bh[tn], acc[tm][tn], 0, 0, 0);
                }
        }
    };

    stage(0, 0);
    int cur = 0;
    for (int ks = 0; ks < D_DIM / BK; ++ks) {
        __syncthreads();                    // implicit vmcnt drain: buf[cur] DMAs landed,
                                            // and all waves done reading buf[cur^1]
        if (ks + 1 < D_DIM / BK) stage(cur ^ 1, (ks + 1) * BK);
        compute(cur);
        cur ^= 1;
    }

    // Epilogue: C/D layout (m74): col = lane&31, row = (reg&3) + 8*(reg>>2) + 4*(lane>>5)
    #pragma unroll
    for (int tn = 0; tn < 4; ++tn) {
        const int gcol = wn * 128 + tn * 32 + cl;
        const bool isbeta = (gcol >= 192);
        const float bias = isbeta ? bb[gcol - 192] : 0.f;
        #pragma unroll
        for (int tm = 0; tm < 2; ++tm) {
            #pragma unroll
            for (int r = 0; r < 16; ++r) {
                const int rowin = (r & 3) + 8 * (r >> 2) + 4 * kh;
                const size_t grow = (size_t)(m0 + wm * 64 + tm * 32 + rowin);
                float v = acc[tm][tn][r];
                if (isbeta) v = sigmoid_fast(v + bias);
                proj[grow * NT + gcol] = v;
            }
        }
    }
}

// ======================= k-normalization (unchanged) =======================
__global__ __launch_bounds__(256) void knorm_kernel(float* __restrict__ proj)
{
    const int w = (int)((blockIdx.x * blockDim.x + threadIdx.x) >> 6);
    const int lane = threadIdx.x & 63;
    float k = proj[(size_t)w * NT + lane];
    float s = k * k;
    #pragma unroll
    for (int off = 32; off; off >>= 1) s += __shfl_xor(s, off, 64);
    proj[(size_t)w * NT + lane] = k * fast_rcp(sqrtf(s) + EPSV);
}

// ======================= recurrence (unchanged this round) =======================
__device__ __forceinline__ void step_body(float4& s, const float4 kn, const float4 q,
                                          const float vC, const float beC,
                                          int sp, int l, float& ysel)
{
    float y2 = (s.x * kn.x + s.y * kn.y) + (s.z * kn.z + s.w * kn.w);
    y2 = reduce16(y2);
    const float dC = fmaf(-TWO_LOG2E, y2, vC);
    const float bsx = beC * s.x, bsy = beC * s.y;
    const float bsz = beC * s.z, bsw = beC * s.w;
    s.x = tanh_from_scaled(fmaf(dC, kn.x, bsx));
    s.y = tanh_from_scaled(fmaf(dC, kn.y, bsy));
    s.z = tanh_from_scaled(fmaf(dC, kn.z, bsz));
    s.w = tanh_from_scaled(fmaf(dC, kn.w, bsw));
    float y1 = (s.x * q.x + s.y * q.y) + (s.z * q.z + s.w * q.w);
    y1 = reduce16(y1);
    ysel = (l == sp) ? y1 : ysel;
}

__device__ __forceinline__ void phase16(const float (*buf)[256], int t0,
                                        float4& s, int l, int i, int b,
                                        float* __restrict__ out)
{
    const float* s0 = &buf[0][0];
    const float* s1 = &buf[1][0];
    float4 kn0 = *(const float4*)(s0 + 4 * l);
    float4 q0  = *(const float4*)(s0 + 128 + 4 * l);
    float  vC0 = s0[64 + i] * TWO_LOG2E;
    float  beC0= s0[192 + i] * TWO_LOG2E;
    float4 kn1 = *(const float4*)(s1 + 4 * l);
    float4 q1  = *(const float4*)(s1 + 128 + 4 * l);
    float  vC1 = s1[64 + i] * TWO_LOG2E;
    float  beC1= s1[192 + i] * TWO_LOG2E;

    float ysel = 0.f;
    for (int j = 0; j < 8; ++j) {
        const int sp = 2 * j;
        const int p2 = (sp + 2 < 16) ? sp + 2 : 15;
        const int p3 = (sp + 3 < 16) ? sp + 3 : 15;
        const float* sA = &buf[p2][0];
        const float* sB = &buf[p3][0];
        float4 knA = *(const float4*)(sA + 4 * l);
        float4 qA  = *(const float4*)(sA + 128 + 4 * l);
        float  vCA = sA[64 + i] * TWO_LOG2E;
        float  beCA= sA[192 + i] * TWO_LOG2E;
        float4 knB = *(const float4*)(sB + 4 * l);
        float4 qB  = *(const float4*)(sB + 128 + 4 * l);
        float  vCB = sB[64 + i] * TWO_LOG2E;
        float  beCB= sB[192 + i] * TWO_LOG2E;

        step_body(s, kn0, q0, vC0, beC0, sp,     l, ysel);
        step_body(s, kn1, q1, vC1, beC1, sp + 1, l, ysel);

        kn0 = knA; q0 = qA; vC0 = vCA; beC0 = beCA;
        kn1 = knB; q1 = qB; vC1 = vCB; beC1 = beCB;
    }
    const float w = ysel;
    out[(size_t)(t0 + l) * (B_DIM * N_DIM) + b * 64 + i] = w * w * sigmoid_fast(w);
}

__global__ __launch_bounds__(128, 1) void recur6_kernel(
    const float* __restrict__ proj,
    const float* __restrict__ S0,
    float* __restrict__ out)   // [T,B,N] then S_final [B,N,N]
{
    __shared__ float bufA[16][256];
    __shared__ float bufB[16][256];

    const int wid  = blockIdx.x;          // [0,256)
    const int wv   = threadIdx.x >> 6;    // 0 = consumer, 1 = producer
    const int lane = threadIdx.x & 63;
    const int l = lane & 15;
    const int r = lane >> 4;
    const int b = wid >> 4;
    const int i = ((wid & 15) << 2) + r;

    if (wv == 1) {
        #pragma unroll
        for (int j = 0; j < 16; ++j)
            dma16(proj + ((size_t)j * B_DIM + b) * NT + 4 * lane, &bufA[j][0]);
        __syncthreads();
        for (int t0 = 0; t0 < T_DIM; t0 += 32) {
            #pragma unroll
            for (int j = 0; j < 16; ++j) {
                int row = t0 + 16 + j; if (row > T_DIM - 1) row = T_DIM - 1;
                dma16(proj + ((size_t)row * B_DIM + b) * NT + 4 * lane, &bufB[j][0]);
            }
            __syncthreads();
            #pragma unroll
            for (int j = 0; j < 16; ++j) {
                int row = t0 + 32 + j; if (row > T_DIM - 1) row = T_DIM - 1;
                dma16(proj + ((size_t)row * B_DIM + b) * NT + 4 * lane, &bufA[j][0]);
            }
            __syncthreads();
        }
    } else {
        float4 s = *(const float4*)(S0 + ((size_t)(b * 64 + i) << 6) + 4 * l);
        __syncthreads();
        for (int t0 = 0; t0 < T_DIM; t0 += 32) {
            phase16(bufA, t0, s, l, i, b, out);
            __syncthreads();
            phase16(bufB, t0 + 16, s, l, i, b, out);
            __syncthreads();
        }
        *(float4*)(out + (size_t)T_DIM * B_DIM * N_DIM +
                   ((size_t)(b * 64 + i) << 6) + 4 * l) = s;
    }
}

extern "C" void kernel_launch(void* const* d_in, const int* in_sizes, int n_in,
                              void* d_out, int out_size, void* d_ws, size_t ws_size,
                              hipStream_t stream) {
    const float* x  = (const float*)d_in[0];
    const float* S0 = (const float*)d_in[1];
    const float* Wk = (const float*)d_in[2];
    const float* Wv = (const float*)d_in[3];
    const float* Wq = (const float*)d_in[4];
    const float* Wb = (const float*)d_in[5];
    const float* bb = (const float*)d_in[6];
    float* out  = (float*)d_out;
    float* proj = (float*)d_ws;   // 32768 * 256 floats = 32 MB

    proj_gemm_mfma<<<dim3(32768 / BM), dim3(256), 0, stream>>>(x, Wk, Wv, Wq, Wb, bb, proj);
    knorm_kernel<<<dim3((32768 * 64) / 256), dim3(256), 0, stream>>>(proj);
    recur6_kernel<<<dim3(256), dim3(128), 0, stream>>>(proj, S0, out);
}

// Round 2
// 470.057 us; speedup vs baseline: 1.3358x; 1.1135x over previous
//
#include <hip/hip_runtime.h>
#include <math.h>
#include <stdint.h>

#define T_DIM 2048
#define B_DIM 16
#define D_DIM 1024
#define N_DIM 64
#define EPSV 1e-6f

#define NT 256   // proj row: 0-63 k, 64-127 v, 128-191 q, 192-255 sigmoid(beta)

#define TWO_LOG2E 2.885390081777927f
#define LOG2E     1.4426950408889634f

typedef _Float16 half8 __attribute__((ext_vector_type(8)));
typedef float    f32x16_t __attribute__((ext_vector_type(16)));
union F4H8 { float4 f; half8 h; };

// ---- fast math ----
__device__ __forceinline__ float fast_rcp(float x) {
    return __builtin_amdgcn_rcpf(x);
}
__device__ __forceinline__ float sigmoid_fast(float x) {
    return fast_rcp(1.f + __builtin_amdgcn_exp2f(-LOG2E * x));
}
__device__ __forceinline__ float tanh_from_scaled(float xs) {
    float e = __builtin_amdgcn_exp2f(xs);
    return 1.f - 2.f * fast_rcp(e + 1.f);
}

// DPP all-reduce within each 16-lane row.
template<int CTRL>
__device__ __forceinline__ float dpp_radd(float x) {
    int y = __builtin_amdgcn_update_dpp(0, __float_as_int(x), CTRL, 0xf, 0xf, true);
    return x + __int_as_float(y);
}
__device__ __forceinline__ float reduce16(float x) {
    x = dpp_radd<0xB1>(x);
    x = dpp_radd<0x4E>(x);
    x = dpp_radd<0x124>(x);
    x = dpp_radd<0x128>(x);
    return x;
}

// async global -> LDS DMA, 16 B per lane; LDS base wave-uniform, lane i -> base + 16*i
__device__ __forceinline__ void dma16(const float* g, float* l) {
    __builtin_amdgcn_global_load_lds((const __attribute__((address_space(1))) void*)g,
                                     (__attribute__((address_space(3))) void*)l, 16, 0, 0);
}

// ======================= W prepass =======================
// W2 layout: 16B slots [s][c], s = 2*k8 + plane (k8 = k>>3 in [0,128), plane 0=hi 1=lo),
// c = output col in [0,256). Slot holds 8 consecutive-k fp16 of W[c][k8*8 .. +8).
// This is exactly the 32x32x16 f16 B-fragment order: lane reads [s][col] directly.
__global__ __launch_bounds__(256) void wprep_kernel(
    const float* __restrict__ Wk, const float* __restrict__ Wv,
    const float* __restrict__ Wq, const float* __restrict__ Wb,
    float4* __restrict__ w2)
{
    const int c  = threadIdx.x;           // 0..255
    const int k8 = blockIdx.x;            // 0..127
    const float* Wsrc = (c < 64) ? Wk : (c < 128) ? Wv : (c < 192) ? Wq : Wb;
    const float4* src = (const float4*)(Wsrc + (size_t)(c & 63) * D_DIM + k8 * 8);
    const float4 f0 = src[0], f1 = src[1];
    float f[8] = {f0.x, f0.y, f0.z, f0.w, f1.x, f1.y, f1.z, f1.w};
    F4H8 hi, lo;
    #pragma unroll
    for (int j = 0; j < 8; ++j) {
        _Float16 h = (_Float16)f[j];          // RTN; residual below is exact in f32
        hi.h[j] = h;
        lo.h[j] = (_Float16)(f[j] - (float)h);
    }
    w2[(size_t)(2 * k8)     * 256 + c] = hi.f;
    w2[(size_t)(2 * k8 + 1) * 256 + c] = lo.f;
}

// ======================= MFMA projection GEMM =======================
// proj[m][c] = sum_k x[m][k]*W[c][k] via f16 3-pass: xh*wh + xh*wl + xl*wh.
// BM=64, BN=256 (full), BK=32 fp32 k per step, grid 512 -> 2 blocks/CU.
// Pipeline per iter (one barrier): DMA fp32 x (k+2) | global B loads (k) |
// convert fp32->f16 hi/lo (k+1) | MFMA compute (k).
// LDS slot scheme: row-major [64 rows][8 x 16B slots], phys = logical ^ (row&7)
// -> all LDS ops at the 4-way-conflict floor. DMA keeps linear dest; the XOR is
// applied to the per-lane GLOBAL source (G21) and to every LDS read/write.
#define BM 64

__global__ __launch_bounds__(256) void proj_gemm_mfma(
    const float* __restrict__ x,
    const float4* __restrict__ w2,
    const float* __restrict__ bb,
    float* __restrict__ proj)
{
    __shared__ float  As32[2][BM * 32];   // fp32 staging, 8 KB each
    __shared__ float4 Ahl[2][BM * 8];     // f16 hi/lo slots, 8 KB each

    const int tid  = threadIdx.x;
    const int w    = tid >> 6;            // wave = col-group wn 0..3
    const int lane = tid & 63;
    const int m0   = blockIdx.x * BM;
    const int cl   = lane & 31;
    const int kh   = lane >> 5;           // k-half of the MFMA operand

    f32x16_t acc[2][2] = {};              // [tm][tn], wave tile 64M x 64N

    auto stage = [&](int buf, int t) {    // fp32 x tile for K-step t
        #pragma unroll
        for (int i = 0; i < 2; ++i) {
            const int rb    = w * 16 + i * 8;
            const int row   = rb + (lane >> 3);
            const int sslot = (lane & 7) ^ ((lane >> 3) & 7);   // pre-swizzled source
            dma16(x + (size_t)(m0 + row) * D_DIM + 32 * t + 4 * sslot,
                  &As32[buf][rb * 32]);
        }
    };
    auto convert = [&](int bs, int bd) {  // fp32 -> f16 hi/lo, once per element
        const int row = tid >> 2, c = tid & 3, sw = row & 7;
        const float4* s32 = (const float4*)&As32[bs][0];
        const float4 fA = s32[row * 8 + ((2 * c)     ^ sw)];
        const float4 fB = s32[row * 8 + ((2 * c + 1) ^ sw)];
        float f[8] = {fA.x, fA.y, fA.z, fA.w, fB.x, fB.y, fB.z, fB.w};
        F4H8 hi, lo;
        #pragma unroll
        for (int j = 0; j < 8; ++j) {
            _Float16 h = (_Float16)f[j];
            hi.h[j] = h;
            lo.h[j] = (_Float16)(f[j] - (float)h);
        }
        Ahl[bd][row * 8 + ((2 * c)     ^ sw)] = hi.f;
        Ahl[bd][row * 8 + ((2 * c + 1) ^ sw)] = lo.f;
    };

    stage(0, 0);
    stage(1, 1);
    __syncthreads();          // both fp32 tiles landed
    convert(0, 0);            // Ahl[0] <- step 0
    __syncthreads();

    for (int t = 0; t < 32; ++t) {
        if (t + 2 < 32) stage(t & 1, t + 2);        // As32[t&1] consumed last iter

        // B fragments for step t straight from L2 (frag-ordered w2)
        half8 bh[2][2], bl[2][2];                   // [ksub][tn]
        #pragma unroll
        for (int ks = 0; ks < 2; ++ks) {
            const int ksg = 2 * t + ks;
            #pragma unroll
            for (int tn = 0; tn < 2; ++tn) {
                const int col = w * 64 + tn * 32 + cl;
                F4H8 th, tl;
                th.f = w2[(size_t)(4 * ksg + 2 * kh)     * 256 + col];
                tl.f = w2[(size_t)(4 * ksg + 2 * kh + 1) * 256 + col];
                bh[ks][tn] = th.h; bl[ks][tn] = tl.h;
            }
        }

        if (t + 1 < 32) convert((t + 1) & 1, (t + 1) & 1);   // hides B-load latency

        const float4* At = &Ahl[t & 1][0];
        #pragma unroll
        for (int ks = 0; ks < 2; ++ks) {
            half8 ah[2], al[2];
            #pragma unroll
            for (int tm = 0; tm < 2; ++tm) {
                const int row = tm * 32 + cl;
                const int sw  = row & 7;
                F4H8 th, tl;
                th.f = At[row * 8 + ((4 * ks + 2 * kh)     ^ sw)];
                tl.f = At[row * 8 + ((4 * ks + 2 * kh + 1) ^ sw)];
                ah[tm] = th.h; al[tm] = tl.h;
            }
            #pragma unroll
            for (int tm = 0; tm < 2; ++tm)
                #pragma unroll
                for (int tn = 0; tn < 2; ++tn) {
                    acc[tm][tn] = __builtin_amdgcn_mfma_f32_32x32x16_f16(ah[tm], bh[ks][tn], acc[tm][tn], 0, 0, 0);
                    acc[tm][tn] = __builtin_amdgcn_mfma_f32_32x32x16_f16(ah[tm], bl[ks][tn], acc[tm][tn], 0, 0, 0);
                    acc[tm][tn] = __builtin_amdgcn_mfma_f32_32x32x16_f16(al[tm], bh[ks][tn], acc[tm][tn], 0, 0, 0);
                }
        }
        __syncthreads();     // drains DMA(t+2); releases As32/Ahl buffers
    }

    // Epilogue: C/D layout col = lane&31, row = (r&3) + 8*(r>>2) + 4*(lane>>5)
    #pragma unroll
    for (int tn = 0; tn < 2; ++tn) {
        const int  gcol   = w * 64 + tn * 32 + cl;
        const bool isbeta = (gcol >= 192);
        const float bias  = isbeta ? bb[gcol - 192] : 0.f;
        #pragma unroll
        for (int tm = 0; tm < 2; ++tm) {
            #pragma unroll
            for (int r = 0; r < 16; ++r) {
                const int rowin = (r & 3) + 8 * (r >> 2) + 4 * kh;
                const size_t grow = (size_t)(m0 + tm * 32 + rowin);
                float v = acc[tm][tn][r];
                if (isbeta) v = sigmoid_fast(v + bias);
                proj[grow * NT + gcol] = v;
            }
        }
    }
}

// ======================= k-normalization (unchanged) =======================
__global__ __launch_bounds__(256) void knorm_kernel(float* __restrict__ proj)
{
    const int w = (int)((blockIdx.x * blockDim.x + threadIdx.x) >> 6);
    const int lane = threadIdx.x & 63;
    float k = proj[(size_t)w * NT + lane];
    float s = k * k;
    #pragma unroll
    for (int off = 32; off; off >>= 1) s += __shfl_xor(s, off, 64);
    proj[(size_t)w * NT + lane] = k * fast_rcp(sqrtf(s) + EPSV);
}

// ======================= recurrence (unchanged this round) =======================
__device__ __forceinline__ void step_body(float4& s, const float4 kn, const float4 q,
                                          const float vC, const float beC,
                                          int sp, int l, float& ysel)
{
    float y2 = (s.x * kn.x + s.y * kn.y) + (s.z * kn.z + s.w * kn.w);
    y2 = reduce16(y2);
    const float dC = fmaf(-TWO_LOG2E, y2, vC);
    const float bsx = beC * s.x, bsy = beC * s.y;
    const float bsz = beC * s.z, bsw = beC * s.w;
    s.x = tanh_from_scaled(fmaf(dC, kn.x, bsx));
    s.y = tanh_from_scaled(fmaf(dC, kn.y, bsy));
    s.z = tanh_from_scaled(fmaf(dC, kn.z, bsz));
    s.w = tanh_from_scaled(fmaf(dC, kn.w, bsw));
    float y1 = (s.x * q.x + s.y * q.y) + (s.z * q.z + s.w * q.w);
    y1 = reduce16(y1);
    ysel = (l == sp) ? y1 : ysel;
}

__device__ __forceinline__ void phase16(const float (*buf)[256], int t0,
                                        float4& s, int l, int i, int b,
                                        float* __restrict__ out)
{
    const float* s0 = &buf[0][0];
    const float* s1 = &buf[1][0];
    float4 kn0 = *(const float4*)(s0 + 4 * l);
    float4 q0  = *(const float4*)(s0 + 128 + 4 * l);
    float  vC0 = s0[64 + i] * TWO_LOG2E;
    float  beC0= s0[192 + i] * TWO_LOG2E;
    float4 kn1 = *(const float4*)(s1 + 4 * l);
    float4 q1  = *(const float4*)(s1 + 128 + 4 * l);
    float  vC1 = s1[64 + i] * TWO_LOG2E;
    float  beC1= s1[192 + i] * TWO_LOG2E;

    float ysel = 0.f;
    for (int j = 0; j < 8; ++j) {
        const int sp = 2 * j;
        const int p2 = (sp + 2 < 16) ? sp + 2 : 15;
        const int p3 = (sp + 3 < 16) ? sp + 3 : 15;
        const float* sA = &buf[p2][0];
        const float* sB = &buf[p3][0];
        float4 knA = *(const float4*)(sA + 4 * l);
        float4 qA  = *(const float4*)(sA + 128 + 4 * l);
        float  vCA = sA[64 + i] * TWO_LOG2E;
        float  beCA= sA[192 + i] * TWO_LOG2E;
        float4 knB = *(const float4*)(sB + 4 * l);
        float4 qB  = *(const float4*)(sB + 128 + 4 * l);
        float  vCB = sB[64 + i] * TWO_LOG2E;
        float  beCB= sB[192 + i] * TWO_LOG2E;

        step_body(s, kn0, q0, vC0, beC0, sp,     l, ysel);
        step_body(s, kn1, q1, vC1, beC1, sp + 1, l, ysel);

        kn0 = knA; q0 = qA; vC0 = vCA; beC0 = beCA;
        kn1 = knB; q1 = qB; vC1 = vCB; beC1 = beCB;
    }
    const float w = ysel;
    out[(size_t)(t0 + l) * (B_DIM * N_DIM) + b * 64 + i] = w * w * sigmoid_fast(w);
}

__global__ __launch_bounds__(128, 1) void recur6_kernel(
    const float* __restrict__ proj,
    const float* __restrict__ S0,
    float* __restrict__ out)   // [T,B,N] then S_final [B,N,N]
{
    __shared__ float bufA[16][256];
    __shared__ float bufB[16][256];

    const int wid  = blockIdx.x;          // [0,256)
    const int wv   = threadIdx.x >> 6;    // 0 = consumer, 1 = producer
    const int lane = threadIdx.x & 63;
    const int l = lane & 15;
    const int r = lane >> 4;
    const int b = wid >> 4;
    const int i = ((wid & 15) << 2) + r;

    if (wv == 1) {
        #pragma unroll
        for (int j = 0; j < 16; ++j)
            dma16(proj + ((size_t)j * B_DIM + b) * NT + 4 * lane, &bufA[j][0]);
        __syncthreads();
        for (int t0 = 0; t0 < T_DIM; t0 += 32) {
            #pragma unroll
            for (int j = 0; j < 16; ++j) {
                int row = t0 + 16 + j; if (row > T_DIM - 1) row = T_DIM - 1;
                dma16(proj + ((size_t)row * B_DIM + b) * NT + 4 * lane, &bufB[j][0]);
            }
            __syncthreads();
            #pragma unroll
            for (int j = 0; j < 16; ++j) {
                int row = t0 + 32 + j; if (row > T_DIM - 1) row = T_DIM - 1;
                dma16(proj + ((size_t)row * B_DIM + b) * NT + 4 * lane, &bufA[j][0]);
            }
            __syncthreads();
        }
    } else {
        float4 s = *(const float4*)(S0 + ((size_t)(b * 64 + i) << 6) + 4 * l);
        __syncthreads();
        for (int t0 = 0; t0 < T_DIM; t0 += 32) {
            phase16(bufA, t0, s, l, i, b, out);
            __syncthreads();
            phase16(bufB, t0 + 16, s, l, i, b, out);
            __syncthreads();
        }
        *(float4*)(out + (size_t)T_DIM * B_DIM * N_DIM +
                   ((size_t)(b * 64 + i) << 6) + 4 * l) = s;
    }
}

extern "C" void kernel_launch(void* const* d_in, const int* in_sizes, int n_in,
                              void* d_out, int out_size, void* d_ws, size_t ws_size,
                              hipStream_t stream) {
    const float* x  = (const float*)d_in[0];
    const float* S0 = (const float*)d_in[1];
    const float* Wk = (const float*)d_in[2];
    const float* Wv = (const float*)d_in[3];
    const float* Wq = (const float*)d_in[4];
    const float* Wb = (const float*)d_in[5];
    const float* bb = (const float*)d_in[6];
    float* out  = (float*)d_out;
    float* proj = (float*)d_ws;                       // 32768*256 f32 = 32 MB
    float4* w2  = (float4*)((char*)d_ws + (size_t)32768 * 256 * 4);   // +1 MB

    wprep_kernel<<<dim3(128), dim3(256), 0, stream>>>(Wk, Wv, Wq, Wb, w2);
    proj_gemm_mfma<<<dim3(32768 / BM), dim3(256), 0, stream>>>(x, w2, bb, proj);
    knorm_kernel<<<dim3((32768 * 64) / 256), dim3(256), 0, stream>>>(proj);
    recur6_kernel<<<dim3(256), dim3(128), 0, stream>>>(proj, S0, out);
}